// Round 6
// baseline (200.041 us; speedup 1.0000x reference)
//
#include <hip/hip_runtime.h>
#include <hip/hip_bf16.h>

#define NN 50000
#define EE 800000
#define CC 64
#define HH 2
#define LL 3
#define CAP 64     // slots per node (Poisson(16): P(>=64) ~ 1e-13)
#define NB 782     // dst buckets of 64 nodes: (50000+63)/64
#define BCAP 1280  // per-bucket capacity (mean 1023, +8 sigma)
#define CHUNK 8192 // edges per k_bin block
#define NBLK ((EE + CHUNK - 1) / CHUNK)   // 98

// R17 = R16 (packed fp32 math, proven build) + software-pipelined gather in
// k_gat. R16 showed a 25% issue cut bought only 5%: k_gat is latency-bound
// (VALUBusy ~55% at ~5 waves/SIMD = ~45% all-waves-stalled on vmcnt).
// Pipeline: (a) first gather issued BEFORE the self-loop math (covers its
// latency); (b) 1-deep rotating prefetch in the edge loop (iter i+1's loads
// in flight while iter i computes; last-trip prefetch clamps to current p ->
// L1 hit, no OOB). Accumulation order unchanged -> identical numerics.

// ---------------- build (R13 verbatim) ----------------

__global__ __launch_bounds__(1024) void k_bin(const int* __restrict__ ei,
                                              int* __restrict__ bcnt,
                                              unsigned int* __restrict__ bucket) {
    __shared__ unsigned int stash[CHUNK];
    __shared__ int hist[NB];
    __shared__ int rank[NB];
    __shared__ int base[NB];

    int c0 = blockIdx.x * CHUNK;
    int n = EE - c0; if (n > CHUNK) n = CHUNK;

    for (int b = threadIdx.x; b < NB; b += 1024) { hist[b] = 0; rank[b] = 0; }
    __syncthreads();

    for (int k = threadIdx.x; k < n; k += 1024) {
        unsigned int s = (unsigned int)ei[c0 + k];
        unsigned int d = (unsigned int)ei[EE + c0 + k];
        stash[k] = (d << 16) | s;
        atomicAdd(&hist[d >> 6], 1);
    }
    __syncthreads();

    for (int b = threadIdx.x; b < NB; b += 1024) {
        int c = hist[b];
        base[b] = c ? atomicAdd(&bcnt[b], c) : 0;
    }
    __syncthreads();

    for (int k = threadIdx.x; k < n; k += 1024) {
        unsigned int pk = stash[k];
        int b = (int)(pk >> 22);
        int r = atomicAdd(&rank[b], 1);
        int pos = base[b] + r;
        if (pos < BCAP) bucket[(size_t)b * BCAP + pos] = pk;
    }
}

__global__ __launch_bounds__(256) void k_place(const unsigned int* __restrict__ bucket,
                                               const int* __restrict__ bcnt,
                                               int* __restrict__ cnt,
                                               unsigned short* __restrict__ slots) {
    __shared__ int lcnt[64];
    int b = blockIdx.x;
    if (threadIdx.x < 64) lcnt[threadIdx.x] = 0;
    __syncthreads();
    int node0 = b << 6;
    int m = bcnt[b];
    if (m > BCAP) m = BCAP;
    const unsigned int* src = bucket + (size_t)b * BCAP;
    for (int i = threadIdx.x; i < m; i += 256) {
        unsigned int pk = src[i];
        int d = (int)(pk >> 16);
        int s = (int)(pk & 0xFFFFu);
        int pos = atomicAdd(&lcnt[d - node0], 1);
        if (pos < CAP) slots[(size_t)d * CAP + pos] = (unsigned short)s;
    }
    __syncthreads();
    if (threadIdx.x < 64) {
        int node = node0 + threadIdx.x;
        if (node < NN) cnt[node] = lcnt[threadIdx.x];
    }
}

// ---------------- fused GAT layer ----------------

typedef float v2f __attribute__((ext_vector_type(2)));

template <int CTRL>
__device__ __forceinline__ float dpp_add(float v) {
    int t = __builtin_amdgcn_update_dpp(0, __float_as_int(v), CTRL, 0xF, 0xF, true);
    return v + __int_as_float(t);
}

// sum over the 16 lanes of a subgroup (subgroups are 16-lane aligned);
// fused v_add_f32_dpp on the VALU pipe — no ds_swizzle/lgkm stall (R13 win)
__device__ __forceinline__ float red16(float v) {
    v = dpp_add<0xB1>(v);    // quad_perm [1,0,3,2] = lane^1
    v = dpp_add<0x4E>(v);    // quad_perm [2,3,0,1] = lane^2
    v = dpp_add<0x141>(v);   // row_half_mirror     = lane^4 (quads uniform)
    v = dpp_add<0x140>(v);   // row_mirror          = lane^8 (halves uniform)
    return v;
}

// leaky_relu on a packed pair: pk_mul + pk_max
__device__ __forceinline__ v2f lk2(v2f v) {
    v2f t = 0.2f * v;
    return __builtin_elementwise_max(v, t);
}

__device__ __forceinline__ v2f fma2(v2f a, v2f b, v2f c) {
    return __builtin_elementwise_fma(a, b, c);
}

template <bool FIRST>
__global__ __launch_bounds__(256) void k_gat(const float* __restrict__ h,
                                             const int* __restrict__ cnt,
                                             const unsigned short* __restrict__ slots,
                                             const float* __restrict__ att_l,
                                             const float* __restrict__ bias_l,
                                             float* __restrict__ h_out,
                                             float* __restrict__ acc, int n) {
    int wid = threadIdx.x >> 6;
    int lane = threadIdx.x & 63;
    int node = blockIdx.x * 4 + wid;
    if (node >= n) return;
    int sub = lane >> 4, q = lane & 15;
    unsigned qb = (unsigned)q << 4;              // byte offset of quad in a row
    const char* hb = (const char*)h;
    const v2f* attv = (const v2f*)att_l;
    v2f a0_01 = attv[2 * q],      a0_23 = attv[2 * q + 1];
    v2f a1_01 = attv[32 + 2 * q], a1_23 = attv[32 + 2 * q + 1];
    float4 hd = *(const float4*)(hb + (((unsigned)node << 8) + qb));
    v2f hd01 = {hd.x, hd.y}, hd23 = {hd.z, hd.w};
    int deg = cnt[node];
    if (deg > CAP) deg = CAP;
    const unsigned* rowu = (const unsigned*)(slots + (size_t)node * CAP);

    // ---- pipeline stage 0: issue the first gather before self-loop math ----
    int npair = deg >> 1;
    int p = sub;
    bool act = p < npair;
    unsigned pk = 0;
    float4 va, vb;
    if (act) {
        pk = rowu[p];
        va = *(const float4*)(hb + (((pk & 0xFFFFu) << 8) + qb));
        vb = *(const float4*)(hb + (((pk >> 16) << 8) + qb));
    }

    float s0, s1;
    v2f A0_01, A0_23, A1_01, A1_23;

    // self-loop (runs while the first gather is in flight): all 4 subgroups,
    // weight 1/4 (merge sums restore 1x) — no branch
    {
        v2f u01 = lk2(hd01 + hd01), u23 = lk2(hd23 + hd23);
        v2f d0 = fma2(u23, a0_23, u01 * a0_01);
        v2f d1 = fma2(u23, a1_23, u01 * a1_01);
        float p0 = red16(d0.x + d0.y);
        float p1 = red16(d1.x + d1.y);
        float e0 = 0.25f * __expf(p0), e1 = 0.25f * __expf(p1);
        s0 = e0; s1 = e1;
        A0_01 = e0 * hd01; A0_23 = e0 * hd23;
        A1_01 = e1 * hd01; A1_23 = e1 * hd23;
    }

    // ---- main loop: 1-deep rotating prefetch ----
    // subgroup takes edge pairs (2p, 2p+1); iter i+1's loads issue before
    // iter i's compute. Last trip re-loads p (L1 hit) — no OOB address.
    if (act) {
        for (;;) {
            int pn = p + 4;
            bool more = pn < npair;
            unsigned pk_n = rowu[more ? pn : p];
            float4 va_n = *(const float4*)(hb + (((pk_n & 0xFFFFu) << 8) + qb));
            float4 vb_n = *(const float4*)(hb + (((pk_n >> 16) << 8) + qb));

            v2f va01 = {va.x, va.y}, va23 = {va.z, va.w};
            v2f vb01 = {vb.x, vb.y}, vb23 = {vb.z, vb.w};
            v2f ma01 = lk2(va01 + hd01), ma23 = lk2(va23 + hd23);
            v2f mb01 = lk2(vb01 + hd01), mb23 = lk2(vb23 + hd23);
            v2f da0 = fma2(ma23, a0_23, ma01 * a0_01);
            v2f da1 = fma2(ma23, a1_23, ma01 * a1_01);
            v2f db0 = fma2(mb23, a0_23, mb01 * a0_01);
            v2f db1 = fma2(mb23, a1_23, mb01 * a1_01);
            float pa0 = red16(da0.x + da0.y);
            float pa1 = red16(da1.x + da1.y);
            float pb0 = red16(db0.x + db0.y);
            float pb1 = red16(db1.x + db1.y);
            float ea0 = __expf(pa0), ea1 = __expf(pa1);
            float eb0 = __expf(pb0), eb1 = __expf(pb1);
            s0 += ea0 + eb0;
            s1 += ea1 + eb1;
            v2f ea0v = {ea0, ea0}, ea1v = {ea1, ea1};
            v2f eb0v = {eb0, eb0}, eb1v = {eb1, eb1};
            A0_01 = fma2(ea0v, va01, fma2(eb0v, vb01, A0_01));
            A0_23 = fma2(ea0v, va23, fma2(eb0v, vb23, A0_23));
            A1_01 = fma2(ea1v, va01, fma2(eb1v, vb01, A1_01));
            A1_23 = fma2(ea1v, va23, fma2(eb1v, vb23, A1_23));

            if (!more) break;
            p = pn; va = va_n; vb = vb_n;
        }
    }

    // tail: one odd edge, handled by one subgroup (uniform per subgroup)
    if (deg & 1) {
        int t = deg - 1;
        if (sub == ((t >> 1) & 3)) {
            unsigned s = ((const unsigned short*)rowu)[t];
            float4 hv = *(const float4*)(hb + ((s << 8) + qb));
            v2f hv01 = {hv.x, hv.y}, hv23 = {hv.z, hv.w};
            v2f m01 = lk2(hv01 + hd01), m23 = lk2(hv23 + hd23);
            v2f d0 = fma2(m23, a0_23, m01 * a0_01);
            v2f d1 = fma2(m23, a1_23, m01 * a1_01);
            float p0 = red16(d0.x + d0.y);
            float p1 = red16(d1.x + d1.y);
            float e0 = __expf(p0), e1 = __expf(p1);
            s0 += e0; s1 += e1;
            v2f e0v = {e0, e0}, e1v = {e1, e1};
            A0_01 = fma2(e0v, hv01, A0_01); A0_23 = fma2(e0v, hv23, A0_23);
            A1_01 = fma2(e1v, hv01, A1_01); A1_23 = fma2(e1v, hv23, A1_23);
        }
    }

    // merge the 4 subgroups: plain sums (cross-row — DPP can't, keep shfl)
#pragma unroll
    for (int step = 16; step <= 32; step <<= 1) {
        s0 += __shfl_xor(s0, step);
        s1 += __shfl_xor(s1, step);
        A0_01.x += __shfl_xor(A0_01.x, step); A0_01.y += __shfl_xor(A0_01.y, step);
        A0_23.x += __shfl_xor(A0_23.x, step); A0_23.y += __shfl_xor(A0_23.y, step);
        A1_01.x += __shfl_xor(A1_01.x, step); A1_01.y += __shfl_xor(A1_01.y, step);
        A1_23.x += __shfl_xor(A1_23.x, step); A1_23.y += __shfl_xor(A1_23.y, step);
    }

    if (sub == 0) {
        float inv0 = 0.5f / (s0 + 1e-16f);       // fold mean-over-heads
        float inv1 = 0.5f / (s1 + 1e-16f);
        float4 b4 = ((const float4*)bias_l)[q];
        float4 o;
        o.x = A0_01.x * inv0 + A1_01.x * inv1 + b4.x;
        o.y = A0_01.y * inv0 + A1_01.y * inv1 + b4.y;
        o.z = A0_23.x * inv0 + A1_23.x * inv1 + b4.z;
        o.w = A0_23.y * inv0 + A1_23.y * inv1 + b4.w;
        ((float4*)h_out)[(size_t)node * 16 + q] = o;
        float4* accp = (float4*)acc + (size_t)node * 16 + q;
        float4 ac;
        if (FIRST) {
            // acc = 0.25*(x + h1); hd holds x's row quad
            ac.x = 0.25f * (hd.x + o.x); ac.y = 0.25f * (hd.y + o.y);
            ac.z = 0.25f * (hd.z + o.z); ac.w = 0.25f * (hd.w + o.w);
        } else {
            ac = *accp;
            ac.x += 0.25f * o.x; ac.y += 0.25f * o.y;
            ac.z += 0.25f * o.z; ac.w += 0.25f * o.w;
        }
        *accp = ac;
    }
}

// ---------------- launch ----------------

static inline size_t align256(size_t x) { return (x + 255) & ~(size_t)255; }

extern "C" void kernel_launch(void* const* d_in, const int* in_sizes, int n_in,
                              void* d_out, int out_size, void* d_ws, size_t ws_size,
                              hipStream_t stream) {
    const float* x    = (const float*)d_in[0];
    const int*   ei   = (const int*)d_in[1];
    const float* att  = (const float*)d_in[2];
    const float* bias = (const float*)d_in[3];
    float* acc = (float*)d_out;   // fp32 output; feats-mean accumulated here

    char* w = (char*)d_ws;
    int* bcnt   = (int*)w;              w += align256((size_t)NB * sizeof(int));
    int* cnt    = (int*)w;              w += align256((size_t)NN * sizeof(int));
    unsigned int* bucket = (unsigned int*)w;
    w += align256((size_t)NB * BCAP * sizeof(unsigned int));
    unsigned short* slots = (unsigned short*)w;
    w += align256((size_t)NN * CAP * sizeof(unsigned short));
    float* hA   = (float*)w;            w += align256((size_t)NN * CC * sizeof(float));
    float* hB   = (float*)w;            w += align256((size_t)NN * CC * sizeof(float));

    const int B = 256;

    // build (per call; ws is re-poisoned before every launch)
    hipMemsetAsync(bcnt, 0, (size_t)NB * sizeof(int), stream);
    k_bin<<<NBLK, 1024, 0, stream>>>(ei, bcnt, bucket);
    k_place<<<NB, B, 0, stream>>>(bucket, bcnt, cnt, slots);

    // 3 fused GAT layers; layer 0 reads x directly and seeds acc = 0.25*(x + h1)
    k_gat<true><<<(NN + 3) / 4, B, 0, stream>>>(
        x, cnt, slots, att, bias, hA, acc, NN);
    k_gat<false><<<(NN + 3) / 4, B, 0, stream>>>(
        hA, cnt, slots, att + (size_t)HH * CC, bias + CC, hB, acc, NN);
    k_gat<false><<<(NN + 3) / 4, B, 0, stream>>>(
        hB, cnt, slots, att + (size_t)2 * HH * CC, bias + 2 * CC, hA, acc, NN);
}

// Round 7
// 193.000 us; speedup vs baseline: 1.0365x; 1.0365x over previous
//
#include <hip/hip_runtime.h>
#include <hip/hip_fp16.h>

#define NN 50000
#define EE 800000
#define CC 64
#define HH 2
#define LL 3
#define CAP 64     // slots per node (Poisson(16): P(>=64) ~ 1e-13)
#define NB 782     // dst buckets of 64 nodes: (50000+63)/64
#define BCAP 1280  // per-bucket capacity (mean 1023, +8 sigma)
#define CHUNK 8192 // edges per k_bin block
#define NBLK ((EE + CHUNK - 1) / CHUNK)   // 98

// R18 = R16 loop structure VERBATIM (unroll-2 packed-fp32 + DPP reduce; R17's
// manual rotation reduced MLP and regressed — reverted) + fp16 storage for the
// intermediate hidden states h1/h2. k_gat is latency-bound on the random row
// gather: 12.8MB fp32 h vs 4MB/XCD L2 -> ~20% HBM misses. fp16 halves the
// gathered working set (6.4MB, ~L2-resident) and halves layer-1/2 HBM fetch.
// All math stays fp32; acc accumulates fp32 epilogue values, so fp16 error
// only enters via layer-2/3 inputs (~2e-4 total vs 3.9e-3 tolerance). Layer 3
// skips its h_out write entirely (only acc is consumed).

// ---------------- build (R13 verbatim) ----------------

__global__ __launch_bounds__(1024) void k_bin(const int* __restrict__ ei,
                                              int* __restrict__ bcnt,
                                              unsigned int* __restrict__ bucket) {
    __shared__ unsigned int stash[CHUNK];
    __shared__ int hist[NB];
    __shared__ int rank[NB];
    __shared__ int base[NB];

    int c0 = blockIdx.x * CHUNK;
    int n = EE - c0; if (n > CHUNK) n = CHUNK;

    for (int b = threadIdx.x; b < NB; b += 1024) { hist[b] = 0; rank[b] = 0; }
    __syncthreads();

    for (int k = threadIdx.x; k < n; k += 1024) {
        unsigned int s = (unsigned int)ei[c0 + k];
        unsigned int d = (unsigned int)ei[EE + c0 + k];
        stash[k] = (d << 16) | s;
        atomicAdd(&hist[d >> 6], 1);
    }
    __syncthreads();

    for (int b = threadIdx.x; b < NB; b += 1024) {
        int c = hist[b];
        base[b] = c ? atomicAdd(&bcnt[b], c) : 0;
    }
    __syncthreads();

    for (int k = threadIdx.x; k < n; k += 1024) {
        unsigned int pk = stash[k];
        int b = (int)(pk >> 22);
        int r = atomicAdd(&rank[b], 1);
        int pos = base[b] + r;
        if (pos < BCAP) bucket[(size_t)b * BCAP + pos] = pk;
    }
}

__global__ __launch_bounds__(256) void k_place(const unsigned int* __restrict__ bucket,
                                               const int* __restrict__ bcnt,
                                               int* __restrict__ cnt,
                                               unsigned short* __restrict__ slots) {
    __shared__ int lcnt[64];
    int b = blockIdx.x;
    if (threadIdx.x < 64) lcnt[threadIdx.x] = 0;
    __syncthreads();
    int node0 = b << 6;
    int m = bcnt[b];
    if (m > BCAP) m = BCAP;
    const unsigned int* src = bucket + (size_t)b * BCAP;
    for (int i = threadIdx.x; i < m; i += 256) {
        unsigned int pk = src[i];
        int d = (int)(pk >> 16);
        int s = (int)(pk & 0xFFFFu);
        int pos = atomicAdd(&lcnt[d - node0], 1);
        if (pos < CAP) slots[(size_t)d * CAP + pos] = (unsigned short)s;
    }
    __syncthreads();
    if (threadIdx.x < 64) {
        int node = node0 + threadIdx.x;
        if (node < NN) cnt[node] = lcnt[threadIdx.x];
    }
}

// ---------------- fused GAT layer ----------------

typedef float v2f __attribute__((ext_vector_type(2)));

template <int CTRL>
__device__ __forceinline__ float dpp_add(float v) {
    int t = __builtin_amdgcn_update_dpp(0, __float_as_int(v), CTRL, 0xF, 0xF, true);
    return v + __int_as_float(t);
}

// sum over the 16 lanes of a subgroup (subgroups are 16-lane aligned);
// fused v_add_f32_dpp on the VALU pipe — no ds_swizzle/lgkm stall (R13 win)
__device__ __forceinline__ float red16(float v) {
    v = dpp_add<0xB1>(v);    // quad_perm [1,0,3,2] = lane^1
    v = dpp_add<0x4E>(v);    // quad_perm [2,3,0,1] = lane^2
    v = dpp_add<0x141>(v);   // row_half_mirror     = lane^4 (quads uniform)
    v = dpp_add<0x140>(v);   // row_mirror          = lane^8 (halves uniform)
    return v;
}

// leaky_relu on a packed pair: pk_mul + pk_max
__device__ __forceinline__ v2f lk2(v2f v) {
    v2f t = 0.2f * v;
    return __builtin_elementwise_max(v, t);
}

__device__ __forceinline__ v2f fma2(v2f a, v2f b, v2f c) {
    return __builtin_elementwise_fma(a, b, c);
}

// load a lane's channel quad of row idx; F16 rows are 128B, fp32 rows 256B
template <bool F16>
__device__ __forceinline__ void ldrow(const char* hb, unsigned idx, unsigned q,
                                      v2f& lo, v2f& hi) {
    if constexpr (F16) {
        uint2 u = *(const uint2*)(hb + (idx << 7) + (q << 3));
        float2 fa = __half22float2(__builtin_bit_cast(__half2, u.x));
        float2 fb = __half22float2(__builtin_bit_cast(__half2, u.y));
        lo = (v2f){fa.x, fa.y}; hi = (v2f){fb.x, fb.y};
    } else {
        float4 v = *(const float4*)(hb + (idx << 8) + (q << 4));
        lo = (v2f){v.x, v.y}; hi = (v2f){v.z, v.w};
    }
}

// FIRST: input is fp32 x, seeds acc = 0.25*(x + o). !FIRST: input is fp16.
// WRITE: store fp16 h_out row (skipped for the last layer — only acc used).
template <bool FIRST, bool WRITE>
__global__ __launch_bounds__(256) void k_gat(const void* __restrict__ hin,
                                             const int* __restrict__ cnt,
                                             const unsigned short* __restrict__ slots,
                                             const float* __restrict__ att_l,
                                             const float* __restrict__ bias_l,
                                             void* __restrict__ hout,
                                             float* __restrict__ acc, int n) {
    constexpr bool F16IN = !FIRST;
    int wid = threadIdx.x >> 6;
    int lane = threadIdx.x & 63;
    int node = blockIdx.x * 4 + wid;
    if (node >= n) return;
    int sub = lane >> 4;
    unsigned q = (unsigned)(lane & 15);
    const char* hb = (const char*)hin;
    const v2f* attv = (const v2f*)att_l;
    v2f a0_01 = attv[2 * q],      a0_23 = attv[2 * q + 1];
    v2f a1_01 = attv[32 + 2 * q], a1_23 = attv[32 + 2 * q + 1];
    v2f hd01, hd23;
    ldrow<F16IN>(hb, (unsigned)node, q, hd01, hd23);
    int deg = cnt[node];
    if (deg > CAP) deg = CAP;
    const unsigned* rowu = (const unsigned*)(slots + (size_t)node * CAP);

    float s0, s1;
    v2f A0_01, A0_23, A1_01, A1_23;

    // self-loop: all 4 subgroups, weight 1/4 (merge sums restore 1x) — no branch
    {
        v2f u01 = lk2(hd01 + hd01), u23 = lk2(hd23 + hd23);
        v2f d0 = fma2(u23, a0_23, u01 * a0_01);
        v2f d1 = fma2(u23, a1_23, u01 * a1_01);
        float p0 = red16(d0.x + d0.y);
        float p1 = red16(d1.x + d1.y);
        float e0 = 0.25f * __expf(p0), e1 = 0.25f * __expf(p1);
        s0 = e0; s1 = e1;
        A0_01 = e0 * hd01; A0_23 = e0 * hd23;
        A1_01 = e1 * hd01; A1_23 = e1 * hd23;
    }

    // main loop: subgroup takes edge pairs (2p, 2p+1) — one u32 = both indices.
    // unroll 2: compiler batches two iterations' independent loads (proven R16).
    int npair = deg >> 1;
#pragma unroll 2
    for (int p = sub; p < npair; p += 4) {
        unsigned pk = rowu[p];
        v2f va01, va23, vb01, vb23;
        ldrow<F16IN>(hb, pk & 0xFFFFu, q, va01, va23);
        ldrow<F16IN>(hb, pk >> 16, q, vb01, vb23);
        v2f ma01 = lk2(va01 + hd01), ma23 = lk2(va23 + hd23);
        v2f mb01 = lk2(vb01 + hd01), mb23 = lk2(vb23 + hd23);
        v2f da0 = fma2(ma23, a0_23, ma01 * a0_01);
        v2f da1 = fma2(ma23, a1_23, ma01 * a1_01);
        v2f db0 = fma2(mb23, a0_23, mb01 * a0_01);
        v2f db1 = fma2(mb23, a1_23, mb01 * a1_01);
        float pa0 = red16(da0.x + da0.y);
        float pa1 = red16(da1.x + da1.y);
        float pb0 = red16(db0.x + db0.y);
        float pb1 = red16(db1.x + db1.y);
        float ea0 = __expf(pa0), ea1 = __expf(pa1);
        float eb0 = __expf(pb0), eb1 = __expf(pb1);
        s0 += ea0 + eb0;
        s1 += ea1 + eb1;
        v2f ea0v = {ea0, ea0}, ea1v = {ea1, ea1};
        v2f eb0v = {eb0, eb0}, eb1v = {eb1, eb1};
        A0_01 = fma2(ea0v, va01, fma2(eb0v, vb01, A0_01));
        A0_23 = fma2(ea0v, va23, fma2(eb0v, vb23, A0_23));
        A1_01 = fma2(ea1v, va01, fma2(eb1v, vb01, A1_01));
        A1_23 = fma2(ea1v, va23, fma2(eb1v, vb23, A1_23));
    }

    // tail: one odd edge, handled by one subgroup (uniform per subgroup)
    if (deg & 1) {
        int t = deg - 1;
        if (sub == ((t >> 1) & 3)) {
            unsigned s = ((const unsigned short*)rowu)[t];
            v2f hv01, hv23;
            ldrow<F16IN>(hb, s, q, hv01, hv23);
            v2f m01 = lk2(hv01 + hd01), m23 = lk2(hv23 + hd23);
            v2f d0 = fma2(m23, a0_23, m01 * a0_01);
            v2f d1 = fma2(m23, a1_23, m01 * a1_01);
            float p0 = red16(d0.x + d0.y);
            float p1 = red16(d1.x + d1.y);
            float e0 = __expf(p0), e1 = __expf(p1);
            s0 += e0; s1 += e1;
            v2f e0v = {e0, e0}, e1v = {e1, e1};
            A0_01 = fma2(e0v, hv01, A0_01); A0_23 = fma2(e0v, hv23, A0_23);
            A1_01 = fma2(e1v, hv01, A1_01); A1_23 = fma2(e1v, hv23, A1_23);
        }
    }

    // merge the 4 subgroups: plain sums (cross-row — DPP can't, keep shfl)
#pragma unroll
    for (int step = 16; step <= 32; step <<= 1) {
        s0 += __shfl_xor(s0, step);
        s1 += __shfl_xor(s1, step);
        A0_01.x += __shfl_xor(A0_01.x, step); A0_01.y += __shfl_xor(A0_01.y, step);
        A0_23.x += __shfl_xor(A0_23.x, step); A0_23.y += __shfl_xor(A0_23.y, step);
        A1_01.x += __shfl_xor(A1_01.x, step); A1_01.y += __shfl_xor(A1_01.y, step);
        A1_23.x += __shfl_xor(A1_23.x, step); A1_23.y += __shfl_xor(A1_23.y, step);
    }

    if (sub == 0) {
        float inv0 = 0.5f / (s0 + 1e-16f);       // fold mean-over-heads
        float inv1 = 0.5f / (s1 + 1e-16f);
        float4 b4 = ((const float4*)bias_l)[q];
        v2f o01, o23;
        o01.x = A0_01.x * inv0 + A1_01.x * inv1 + b4.x;
        o01.y = A0_01.y * inv0 + A1_01.y * inv1 + b4.y;
        o23.x = A0_23.x * inv0 + A1_23.x * inv1 + b4.z;
        o23.y = A0_23.y * inv0 + A1_23.y * inv1 + b4.w;
        if constexpr (WRITE) {
            __half2 w0 = __float22half2_rn((float2){o01.x, o01.y});
            __half2 w1 = __float22half2_rn((float2){o23.x, o23.y});
            uint2 u = {__builtin_bit_cast(unsigned, w0),
                       __builtin_bit_cast(unsigned, w1)};
            *(uint2*)((char*)hout + ((size_t)node << 7) + (q << 3)) = u;
        }
        float4* accp = (float4*)acc + (size_t)node * 16 + q;
        float4 ac;
        if (FIRST) {
            // acc = 0.25*(x + h1); hd holds x's row quad (fp32)
            ac.x = 0.25f * (hd01.x + o01.x); ac.y = 0.25f * (hd01.y + o01.y);
            ac.z = 0.25f * (hd23.x + o23.x); ac.w = 0.25f * (hd23.y + o23.y);
        } else {
            ac = *accp;
            ac.x += 0.25f * o01.x; ac.y += 0.25f * o01.y;
            ac.z += 0.25f * o23.x; ac.w += 0.25f * o23.y;
        }
        *accp = ac;
    }
}

// ---------------- launch ----------------

static inline size_t align256(size_t x) { return (x + 255) & ~(size_t)255; }

extern "C" void kernel_launch(void* const* d_in, const int* in_sizes, int n_in,
                              void* d_out, int out_size, void* d_ws, size_t ws_size,
                              hipStream_t stream) {
    const float* x    = (const float*)d_in[0];
    const int*   ei   = (const int*)d_in[1];
    const float* att  = (const float*)d_in[2];
    const float* bias = (const float*)d_in[3];
    float* acc = (float*)d_out;   // fp32 output; feats-mean accumulated here

    char* w = (char*)d_ws;
    int* bcnt   = (int*)w;              w += align256((size_t)NB * sizeof(int));
    int* cnt    = (int*)w;              w += align256((size_t)NN * sizeof(int));
    unsigned int* bucket = (unsigned int*)w;
    w += align256((size_t)NB * BCAP * sizeof(unsigned int));
    unsigned short* slots = (unsigned short*)w;
    w += align256((size_t)NN * CAP * sizeof(unsigned short) + 256);
    void* hA16  = (void*)w;             w += align256((size_t)NN * CC * sizeof(__half));
    void* hB16  = (void*)w;             w += align256((size_t)NN * CC * sizeof(__half));

    const int B = 256;

    // build (per call; ws is re-poisoned before every launch)
    hipMemsetAsync(bcnt, 0, (size_t)NB * sizeof(int), stream);
    k_bin<<<NBLK, 1024, 0, stream>>>(ei, bcnt, bucket);
    k_place<<<NB, B, 0, stream>>>(bucket, bcnt, cnt, slots);

    // 3 fused GAT layers; layer 0 reads fp32 x, seeds acc = 0.25*(x + h1),
    // writes fp16 h1; layers 1/2 gather fp16; layer 2 skips h_out entirely.
    k_gat<true, true><<<(NN + 3) / 4, B, 0, stream>>>(
        x, cnt, slots, att, bias, hA16, acc, NN);
    k_gat<false, true><<<(NN + 3) / 4, B, 0, stream>>>(
        hA16, cnt, slots, att + (size_t)HH * CC, bias + CC, hB16, acc, NN);
    k_gat<false, false><<<(NN + 3) / 4, B, 0, stream>>>(
        hB16, cnt, slots, att + (size_t)2 * HH * CC, bias + 2 * CC, nullptr, acc, NN);
}